// Round 11
// baseline (281.847 us; speedup 1.0000x reference)
//
#include <hip/hip_runtime.h>

#define LL 4096
#define HH 64
#define WWD 64
#define DM 96
#define EE 192
#define NN 16
#define RR 6
#define KBB 8   // N_DIRS * B
#define BB 2
#define CH 128  // number of chunks
#define CLEN 32 // chunk length
#define SID (KBB * EE * NN)  // 24576 states

// ---------------- Kernel 1: in_proj GEMM ----------------
__global__ __launch_bounds__(256) void k_inproj(const float* __restrict__ x,
                                                const float* __restrict__ W,
                                                float* __restrict__ xbuf,
                                                float* __restrict__ zbuf) {
    __shared__ float As[96][64];
    __shared__ float Ws[96][64];
    int bm = blockIdx.x;
    int bn = blockIdx.y;
    int l0 = bm * 64;
    int b  = l0 >> 12;
    int lb = l0 & (LL - 1);
    int j0 = bn * 64;
    int t  = threadIdx.x;

    for (int i = t; i < 96 * 64; i += 256) {
        int d = i >> 6, ml = i & 63;
        As[d][ml] = x[((size_t)b * 96 + d) * LL + lb + ml];
    }
    for (int i = t; i < 96 * 64; i += 256) {
        int jn = i / 96, d = i - jn * 96;
        Ws[d][jn] = W[(size_t)(j0 + jn) * 96 + d];
    }
    __syncthreads();

    int tx = t & 15, ty = t >> 4;
    float acc[4][4] = {};
    for (int d = 0; d < 96; d++) {
        float a[4], bbv[4];
        for (int i = 0; i < 4; i++) a[i] = As[d][ty * 4 + i];
        for (int j = 0; j < 4; j++) bbv[j] = Ws[d][tx * 4 + j];
        for (int i = 0; i < 4; i++)
            for (int j = 0; j < 4; j++) acc[i][j] = fmaf(a[i], bbv[j], acc[i][j]);
    }
    for (int i = 0; i < 4; i++) {
        int l = lb + ty * 4 + i;
        for (int j = 0; j < 4; j++) {
            int jj = j0 + tx * 4 + j;
            if (jj < EE)
                xbuf[((size_t)b * EE + jj) * LL + l] = acc[i][j];
            else
                zbuf[((size_t)b * LL + l) * EE + (jj - EE)] = acc[i][j];
        }
    }
}

// ---------------- Kernel 2: depthwise 3x3 conv + bias + SiLU (+ transpose out) ----------------
__global__ __launch_bounds__(256) void k_conv(const float* __restrict__ xbuf,
                                              const float* __restrict__ cw,
                                              const float* __restrict__ cb,
                                              float* __restrict__ xconv,
                                              float* __restrict__ xconv_t) {
    __shared__ float T[32][33];
    int l0 = blockIdx.x * 32;
    int e0 = blockIdx.y * 32;
    int b  = blockIdx.z;
    int t  = threadIdx.x;
    int tp = t & 31, teo = t >> 5;

    int pos = l0 + tp;
    int h = pos >> 6, w = pos & 63;
    #pragma unroll
    for (int j = 0; j < 4; j++) {
        int ee = j * 8 + teo;
        int e = e0 + ee;
        const float* src = xbuf + ((size_t)b * EE + e) * LL;
        const float* wgt = cw + e * 9;
        float acc = cb[e];
        #pragma unroll
        for (int dh = -1; dh <= 1; dh++) {
            int hh = h + dh;
            if (hh < 0 || hh >= HH) continue;
            #pragma unroll
            for (int dw = -1; dw <= 1; dw++) {
                int w2 = w + dw;
                if (w2 < 0 || w2 >= WWD) continue;
                acc = fmaf(src[hh * WWD + w2], wgt[(dh + 1) * 3 + (dw + 1)], acc);
            }
        }
        float v = acc / (1.f + __expf(-acc));
        xconv[((size_t)b * EE + e) * LL + pos] = v;
        T[ee][tp] = v;
    }
    __syncthreads();
    for (int i = t; i < 32 * 32; i += 256) {
        int p = i >> 5, ee = i & 31;
        xconv_t[((size_t)b * LL + l0 + p) * EE + e0 + ee] = T[ee][p];
    }
}

__device__ __forceinline__ int seq_of_spatial(int k, int idx) {
    if (k == 0) return idx;
    if (k == 1) return LL - 1 - idx;
    int p = ((idx & 63) << 6) | (idx >> 6);
    if (k == 2) return p;
    return LL - 1 - p;
}

__device__ __forceinline__ int spatial_of_seq(int k, int l) {
    int lp = (k & 1) ? (LL - 1 - l) : l;
    return (k >= 2) ? (((lp & 63) << 6) | (lp >> 6)) : lp;
}

// ---------------- Kernel 3 v6: x_proj + dt_proj + softplus ----------------
// v5 + occupancy (4 blocks/CU via launch_bounds(256,4); LDS 34.4KB x4 fits in
// 160KB) + explicit 2-stage software pipeline: prefetch next 4 e's X loads
// while FMA-ing current 4. unroll 1 kept (v4's full unroll spilled to scratch).
__global__ __launch_bounds__(256, 4) void k_proj(const float* __restrict__ xconv,
                                                 const float* __restrict__ xpw,
                                                 const float* __restrict__ dtw,
                                                 const float* __restrict__ dtb,
                                                 float* __restrict__ dtbuf,
                                                 float* __restrict__ Bbuf,
                                                 float* __restrict__ Cbuf) {
    __shared__ float Ws[EE * 38 + 40];  // +pad (no OOB for aliased reads)
    __shared__ float PR[32][8];    // dt_low  (cols 0..5)
    __shared__ float BC[32][33];   // B(0..15) C(16..31)
    int l0 = blockIdx.x * 32;
    int b  = blockIdx.y;
    int k  = blockIdx.z;
    int t  = threadIdx.x;
    int pg = t >> 5;       // 0..7 -> 4 positions each
    int oc = t & 31;       // col0 = oc; col1 = oc+32 (lanes oc<6)

    const float* wsrc = xpw + (size_t)k * EE * 38;
    for (int i = t; i < EE * 38; i += 256) Ws[i] = wsrc[i];
    __syncthreads();

    // lanes oc>=6 read an aliased valid slot; their acc1 is garbage, never stored
    int oc2 = oc + ((oc < 6) ? 32 : 0);

    const float* xbase = xconv + (size_t)b * EE * LL + l0 + 4 * pg;

    float acc0[4] = {}, acc1[4] = {};
    float4 xv[4];
    #pragma unroll
    for (int j = 0; j < 4; j++)
        xv[j] = *(const float4*)&xbase[(size_t)j * LL];

    #pragma unroll 1
    for (int e0 = 0; e0 < EE; e0 += 4) {
        float4 xn[4];
        if (e0 + 4 < EE) {
            #pragma unroll
            for (int j = 0; j < 4; j++)
                xn[j] = *(const float4*)&xbase[(size_t)(e0 + 4 + j) * LL];
        }
        float w0[4], w1[4];
        #pragma unroll
        for (int j = 0; j < 4; j++) {
            w0[j] = Ws[(e0 + j) * 38 + oc];
            w1[j] = Ws[(e0 + j) * 38 + oc2];
        }
        #pragma unroll
        for (int j = 0; j < 4; j++) {
            acc0[0] = fmaf(xv[j].x, w0[j], acc0[0]);
            acc0[1] = fmaf(xv[j].y, w0[j], acc0[1]);
            acc0[2] = fmaf(xv[j].z, w0[j], acc0[2]);
            acc0[3] = fmaf(xv[j].w, w0[j], acc0[3]);
            acc1[0] = fmaf(xv[j].x, w1[j], acc1[0]);
            acc1[1] = fmaf(xv[j].y, w1[j], acc1[1]);
            acc1[2] = fmaf(xv[j].z, w1[j], acc1[2]);
            acc1[3] = fmaf(xv[j].w, w1[j], acc1[3]);
        }
        #pragma unroll
        for (int j = 0; j < 4; j++) xv[j] = xn[j];
    }

    #pragma unroll
    for (int ii = 0; ii < 4; ii++) {
        int p = 4 * pg + ii;
        if (oc < 6) {
            PR[p][oc] = acc0[ii];
            BC[p][oc + 26] = acc1[ii];      // col oc+32 -> C n=oc+10
        } else {
            BC[p][oc - 6] = acc0[ii];       // cols 6..37 -> BC idx 0..25
        }
    }
    __syncthreads();

    int kb = k * 2 + b;
    for (int i = t; i < 32 * 32; i += 256) {
        int pos = i >> 5, c = i & 31;
        int j = seq_of_spatial(k, l0 + pos);
        float v = BC[pos][c];
        if (c < 16) Bbuf[((size_t)kb * LL + j) * NN + c] = v;
        else        Cbuf[((size_t)kb * LL + j) * NN + (c - 16)] = v;
    }

    for (int i = t; i < 32 * EE; i += 256) {
        int pos = i / EE;
        int e = i - pos * EE;
        float s = dtb[k * EE + e];
        const float* wr = dtw + ((size_t)k * EE + e) * RR;
        #pragma unroll
        for (int r = 0; r < RR; r++) s = fmaf(PR[pos][r], wr[r], s);
        float sp = (s > 20.f) ? s : log1pf(__expf(s));
        int j = seq_of_spatial(k, l0 + pos);
        dtbuf[((size_t)kb * LL + j) * EE + e] = sp;
    }
}

// ---------------- Kernel 4a: chunk-local scan (16 states/thread), emit (prodA, h_end) ----------------
__global__ __launch_bounds__(192) void k_scan1(const float* __restrict__ xconv_t,
                                               const float* __restrict__ dtbuf,
                                               const float* __restrict__ Bbuf,
                                               const float* __restrict__ A_log,
                                               float* __restrict__ Ap,
                                               float* __restrict__ He) {
    __shared__ __align__(16) float sB[CLEN][NN];
    int c  = blockIdx.x;
    int kb = blockIdx.y;
    int k = kb >> 1, b = kb & 1;
    int e = threadIdx.x;
    int l0 = c * CLEN;

    for (int i = e; i < CLEN * NN; i += 192)
        ((float*)sB)[i] = Bbuf[((size_t)kb * LL + l0) * NN + i];

    float An[NN], h[NN], pa[NN];
    #pragma unroll
    for (int q = 0; q < 4; q++) {
        float4 al = *(const float4*)&A_log[e * NN + q * 4];
        An[q*4+0] = -__expf(al.x); An[q*4+1] = -__expf(al.y);
        An[q*4+2] = -__expf(al.z); An[q*4+3] = -__expf(al.w);
    }
    #pragma unroll
    for (int n = 0; n < NN; n++) { h[n] = 0.f; pa[n] = 1.f; }
    __syncthreads();

    const float* dtp = dtbuf + ((size_t)kb * LL + l0) * EE + e;
    const float* ub  = xconv_t + (size_t)b * LL * EE + e;

    #pragma unroll 2
    for (int i = 0; i < CLEN; i++) {
        int l = l0 + i;
        int idx = spatial_of_seq(k, l);
        float dtv = dtp[(size_t)i * EE];
        float u   = ub[(size_t)idx * EE];
        float Bv[NN];
        #pragma unroll
        for (int q = 0; q < 4; q++)
            *(float4*)&Bv[q*4] = ((const float4*)&sB[i][0])[q];
        float dtu = dtv * u;
        #pragma unroll
        for (int n = 0; n < NN; n++) {
            float a = __expf(dtv * An[n]);
            h[n] = fmaf(a, h[n], dtu * Bv[n]);
            pa[n] *= a;
        }
    }
    size_t sid = (size_t)c * SID + kb * (EE * NN) + e * NN;
    #pragma unroll
    for (int q = 0; q < 4; q++) {
        *(float4*)&Ap[sid + q*4] = make_float4(pa[q*4], pa[q*4+1], pa[q*4+2], pa[q*4+3]);
        *(float4*)&He[sid + q*4] = make_float4(h[q*4], h[q*4+1], h[q*4+2], h[q*4+3]);
    }
}

// ---------------- Kernel 4b: sequential carry over chunks (Hi written over Ap) ----------------
__global__ __launch_bounds__(256) void k_carry(float* __restrict__ ApHi,
                                               const float* __restrict__ He) {
    int sid = blockIdx.x * 256 + threadIdx.x;
    float h = 0.f;
    #pragma unroll 8
    for (int c = 0; c < CH; c++) {
        size_t ix = (size_t)c * SID + sid;
        float a  = ApHi[ix];
        float he = He[ix];
        ApHi[ix] = h;
        h = fmaf(a, h, he);
    }
}

// ---------------- Kernel 4c: chunk-local scan with carry-in, write ys in SEQUENCE order (no atomics) ----------------
__global__ __launch_bounds__(192) void k_scan2(const float* __restrict__ xconv_t,
                                               const float* __restrict__ dtbuf,
                                               const float* __restrict__ Bbuf,
                                               const float* __restrict__ Cbuf,
                                               const float* __restrict__ A_log,
                                               const float* __restrict__ Dskip,
                                               const float* __restrict__ Hi,
                                               float* __restrict__ ys) {
    __shared__ __align__(16) float sB[CLEN][NN];
    __shared__ __align__(16) float sC[CLEN][NN];
    int c  = blockIdx.x;
    int kb = blockIdx.y;
    int k = kb >> 1, b = kb & 1;
    int e = threadIdx.x;
    int l0 = c * CLEN;

    for (int i = e; i < CLEN * NN; i += 192) {
        ((float*)sB)[i] = Bbuf[((size_t)kb * LL + l0) * NN + i];
        ((float*)sC)[i] = Cbuf[((size_t)kb * LL + l0) * NN + i];
    }

    float An[NN], h[NN];
    #pragma unroll
    for (int q = 0; q < 4; q++) {
        float4 al = *(const float4*)&A_log[e * NN + q * 4];
        An[q*4+0] = -__expf(al.x); An[q*4+1] = -__expf(al.y);
        An[q*4+2] = -__expf(al.z); An[q*4+3] = -__expf(al.w);
    }
    size_t sid = (size_t)c * SID + kb * (EE * NN) + e * NN;
    #pragma unroll
    for (int q = 0; q < 4; q++) {
        float4 hv = *(const float4*)&Hi[sid + q*4];
        h[q*4+0] = hv.x; h[q*4+1] = hv.y; h[q*4+2] = hv.z; h[q*4+3] = hv.w;
    }
    float Dv = Dskip[e];
    __syncthreads();

    const float* dtp = dtbuf + ((size_t)kb * LL + l0) * EE + e;
    const float* ub  = xconv_t + (size_t)b * LL * EE + e;
    float* ysb       = ys + ((size_t)kb * LL + l0) * EE + e;

    #pragma unroll 2
    for (int i = 0; i < CLEN; i++) {
        int l = l0 + i;
        int idx = spatial_of_seq(k, l);
        float dtv = dtp[(size_t)i * EE];
        float u   = ub[(size_t)idx * EE];
        float Bv[NN], Cv[NN];
        #pragma unroll
        for (int q = 0; q < 4; q++) {
            *(float4*)&Bv[q*4] = ((const float4*)&sB[i][0])[q];
            *(float4*)&Cv[q*4] = ((const float4*)&sC[i][0])[q];
        }
        float dtu = dtv * u;
        float y = u * Dv;
        #pragma unroll
        for (int n = 0; n < NN; n++) {
            float a = __expf(dtv * An[n]);
            h[n] = fmaf(a, h[n], dtu * Bv[n]);
            y = fmaf(h[n], Cv[n], y);
        }
        ysb[(size_t)i * EE] = y;
    }
}

// ---------------- Kernel 5: 4-direction gather + LayerNorm + silu(z) gate + out_proj ----------------
__global__ __launch_bounds__(256) void k_out(const float* __restrict__ ys,
                                             const float* __restrict__ zb,
                                             const float* __restrict__ gamma,
                                             const float* __restrict__ beta,
                                             const float* __restrict__ W2,
                                             float* __restrict__ out) {
    __shared__ float sbuf[32][193];
    int b  = blockIdx.x >> 7;
    int l0 = (blockIdx.x & 127) * 32;
    int t  = threadIdx.x;
    int wv = t >> 6, lane = t & 63;

    for (int li = 0; li < 32; li += 4) {
        int l = l0 + li + wv;
        int p = ((l & 63) << 6) | (l >> 6);
        const float* r0 = ys + ((size_t)(0 + b) * LL + l) * EE;
        const float* r1 = ys + ((size_t)(2 + b) * LL + (LL - 1 - l)) * EE;
        const float* r2 = ys + ((size_t)(4 + b) * LL + p) * EE;
        const float* r3 = ys + ((size_t)(6 + b) * LL + (LL - 1 - p)) * EE;
        const float* zrow = zb + ((size_t)b * LL + l) * EE;
        float v[3], zv[3];
        float s = 0.f;
        #pragma unroll
        for (int j = 0; j < 3; j++) {
            int e = lane + 64 * j;
            v[j] = r0[e] + r1[e] + r2[e] + r3[e];
            zv[j] = zrow[e];
            s += v[j];
        }
        for (int m = 1; m < 64; m <<= 1) s += __shfl_xor(s, m);
        float mu = s * (1.f / EE);
        float q = 0.f;
        #pragma unroll
        for (int j = 0; j < 3; j++) { float d = v[j] - mu; q = fmaf(d, d, q); }
        for (int m = 1; m < 64; m <<= 1) q += __shfl_xor(q, m);
        float rs = rsqrtf(q * (1.f / EE) + 1e-5f);
        #pragma unroll
        for (int j = 0; j < 3; j++) {
            int e = lane + 64 * j;
            float yn = (v[j] - mu) * rs * gamma[e] + beta[e];
            float zz = zv[j];
            float sil = zz / (1.f + __expf(-zz));
            sbuf[li + wv][e] = yn * sil;
        }
    }
    __syncthreads();
    for (int o = t; o < DM * 32; o += 256) {
        int d = o >> 5, c = o & 31;
        const float* wr = W2 + (size_t)d * EE;
        float acc = 0.f;
        for (int e = 0; e < EE; e++) acc = fmaf(sbuf[c][e], wr[e], acc);
        out[((size_t)b * DM + d) * LL + l0 + c] = acc;
    }
}

extern "C" void kernel_launch(void* const* d_in, const int* in_sizes, int n_in,
                              void* d_out, int out_size, void* d_ws, size_t ws_size,
                              hipStream_t stream) {
    const float* x      = (const float*)d_in[0];
    const float* in_w   = (const float*)d_in[1];
    const float* conv_w = (const float*)d_in[2];
    const float* conv_b = (const float*)d_in[3];
    const float* xpw    = (const float*)d_in[4];
    const float* dtw    = (const float*)d_in[5];
    const float* dtbias = (const float*)d_in[6];
    const float* A_log  = (const float*)d_in[7];
    const float* Dsk    = (const float*)d_in[8];
    const float* gamma  = (const float*)d_in[9];
    const float* beta   = (const float*)d_in[10];
    const float* W2     = (const float*)d_in[11];
    float* out = (float*)d_out;

    // Workspace layout with lifetime-based aliasing (all sizes in floats).
    // R region hosts xbuf/xconv/He early, then becomes ys after they die.
    // Every ws byte read is written earlier in the same call (0xAA poison safe).
    float* ws      = (float*)d_ws;
    float* zbuf    = ws;                                   // B*L*E
    float* xconv_t = zbuf    + (size_t)BB * LL * EE;       // B*L*E
    float* dtbuf   = xconv_t + (size_t)BB * LL * EE;       // KB*L*E
    float* Bbuf    = dtbuf   + (size_t)KBB * LL * EE;      // KB*L*N
    float* Cbuf    = Bbuf    + (size_t)KBB * LL * NN;      // KB*L*N
    float* ApHi    = Cbuf    + (size_t)KBB * LL * NN;      // CH*SID
    float* R       = ApHi    + (size_t)CH * SID;           // KB*L*E
    float* ys      = R;
    float* xbuf    = R;                                    // dead after k_conv
    float* xconv   = R + (size_t)BB * EE * LL;             // dead after k_proj
    float* He      = R + 2 * (size_t)BB * EE * LL;         // dead after k_carry

    k_inproj<<<dim3(128, 6), 256, 0, stream>>>(x, in_w, xbuf, zbuf);
    k_conv<<<dim3(128, 6, 2), 256, 0, stream>>>(xbuf, conv_w, conv_b, xconv, xconv_t);
    k_proj<<<dim3(128, 2, 4), 256, 0, stream>>>(xconv, xpw, dtw, dtbias, dtbuf, Bbuf, Cbuf);
    k_scan1<<<dim3(CH, KBB), 192, 0, stream>>>(xconv_t, dtbuf, Bbuf, A_log, ApHi, He);
    k_carry<<<SID / 256, 256, 0, stream>>>(ApHi, He);
    k_scan2<<<dim3(CH, KBB), 192, 0, stream>>>(xconv_t, dtbuf, Bbuf, Cbuf, A_log, Dsk, ApHi, ys);
    k_out<<<BB * (LL / 32), 256, 0, stream>>>(ys, zbuf, gamma, beta, W2, out);
}

// Round 12
// 269.752 us; speedup vs baseline: 1.0448x; 1.0448x over previous
//
#include <hip/hip_runtime.h>

#define LL 4096
#define HH 64
#define WWD 64
#define DM 96
#define EE 192
#define NN 16
#define RR 6
#define KBB 8   // N_DIRS * B
#define BB 2
#define CH 128  // number of chunks
#define CLEN 32 // chunk length
#define SID (KBB * EE * NN)  // 24576 states

// ---------------- Kernel 1: in_proj GEMM (float4 LDS) ----------------
__global__ __launch_bounds__(256) void k_inproj(const float* __restrict__ x,
                                                const float* __restrict__ W,
                                                float* __restrict__ xbuf,
                                                float* __restrict__ zbuf) {
    __shared__ __align__(16) float As[96][64];
    __shared__ __align__(16) float Ws[96][64];
    int bm = blockIdx.x;
    int bn = blockIdx.y;
    int l0 = bm * 64;
    int b  = l0 >> 12;
    int lb = l0 & (LL - 1);
    int j0 = bn * 64;
    int t  = threadIdx.x;

    for (int i = t; i < 96 * 16; i += 256) {
        int d = i >> 4, q = i & 15;
        *(float4*)&As[d][4 * q] = *(const float4*)&x[((size_t)b * 96 + d) * LL + lb + 4 * q];
    }
    for (int i = t; i < 96 * 64; i += 256) {
        int jn = i / 96, d = i - jn * 96;
        Ws[d][jn] = W[(size_t)(j0 + jn) * 96 + d];
    }
    __syncthreads();

    int tx = t & 15, ty = t >> 4;
    float acc[4][4] = {};
    for (int d = 0; d < 96; d++) {
        float4 av = *(const float4*)&As[d][ty * 4];
        float4 bv = *(const float4*)&Ws[d][tx * 4];
        float a[4] = {av.x, av.y, av.z, av.w};
        float bbv[4] = {bv.x, bv.y, bv.z, bv.w};
        for (int i = 0; i < 4; i++)
            for (int j = 0; j < 4; j++) acc[i][j] = fmaf(a[i], bbv[j], acc[i][j]);
    }
    for (int i = 0; i < 4; i++) {
        int l = lb + ty * 4 + i;
        for (int j = 0; j < 4; j++) {
            int jj = j0 + tx * 4 + j;
            if (jj < EE)
                xbuf[((size_t)b * EE + jj) * LL + l] = acc[i][j];
            else
                zbuf[((size_t)b * LL + l) * EE + (jj - EE)] = acc[i][j];
        }
    }
}

// ---------------- Kernel 2: depthwise 3x3 conv + bias + SiLU (+ transpose out) ----------------
__global__ __launch_bounds__(256) void k_conv(const float* __restrict__ xbuf,
                                              const float* __restrict__ cw,
                                              const float* __restrict__ cb,
                                              float* __restrict__ xconv,
                                              float* __restrict__ xconv_t) {
    __shared__ float T[32][33];
    int l0 = blockIdx.x * 32;
    int e0 = blockIdx.y * 32;
    int b  = blockIdx.z;
    int t  = threadIdx.x;
    int tp = t & 31, teo = t >> 5;

    int pos = l0 + tp;
    int h = pos >> 6, w = pos & 63;
    #pragma unroll
    for (int j = 0; j < 4; j++) {
        int ee = j * 8 + teo;
        int e = e0 + ee;
        const float* src = xbuf + ((size_t)b * EE + e) * LL;
        const float* wgt = cw + e * 9;
        float acc = cb[e];
        #pragma unroll
        for (int dh = -1; dh <= 1; dh++) {
            int hh = h + dh;
            if (hh < 0 || hh >= HH) continue;
            #pragma unroll
            for (int dw = -1; dw <= 1; dw++) {
                int w2 = w + dw;
                if (w2 < 0 || w2 >= WWD) continue;
                acc = fmaf(src[hh * WWD + w2], wgt[(dh + 1) * 3 + (dw + 1)], acc);
            }
        }
        float v = acc / (1.f + __expf(-acc));
        xconv[((size_t)b * EE + e) * LL + pos] = v;
        T[ee][tp] = v;
    }
    __syncthreads();
    for (int i = t; i < 32 * 32; i += 256) {
        int p = i >> 5, ee = i & 31;
        xconv_t[((size_t)b * LL + l0 + p) * EE + e0 + ee] = T[ee][p];
    }
}

__device__ __forceinline__ int seq_of_spatial(int k, int idx) {
    if (k == 0) return idx;
    if (k == 1) return LL - 1 - idx;
    int p = ((idx & 63) << 6) | (idx >> 6);
    if (k == 2) return p;
    return LL - 1 - p;
}

__device__ __forceinline__ int spatial_of_seq(int k, int l) {
    int lp = (k & 1) ? (LL - 1 - l) : l;
    return (k >= 2) ? (((lp & 63) << 6) | (lp >> 6)) : lp;
}

// ---------------- Kernel 3 v7: x_proj + dt_proj + softplus ----------------
// 8-deep load batch (v4 shape) + "#pragma unroll 1" (prevents v4's full-unroll
// scratch spill: one live batch ~75 VGPR). W staged in LDS via float4.
__global__ __launch_bounds__(256, 4) void k_proj(const float* __restrict__ xconv,
                                                 const float* __restrict__ xpw,
                                                 const float* __restrict__ dtw,
                                                 const float* __restrict__ dtb,
                                                 float* __restrict__ dtbuf,
                                                 float* __restrict__ Bbuf,
                                                 float* __restrict__ Cbuf) {
    __shared__ __align__(16) float Ws[EE * 38 + 40];  // +pad (no OOB for aliased reads)
    __shared__ float PR[32][8];    // dt_low  (cols 0..5)
    __shared__ float BC[32][33];   // B(0..15) C(16..31)
    int l0 = blockIdx.x * 32;
    int b  = blockIdx.y;
    int k  = blockIdx.z;
    int t  = threadIdx.x;
    int pg = t >> 5;       // 0..7 -> 4 positions each
    int oc = t & 31;       // col0 = oc; col1 = oc+32 (lanes oc<6)

    const float* wsrc = xpw + (size_t)k * EE * 38;
    for (int i = t; i < (EE * 38) / 4; i += 256)
        ((float4*)Ws)[i] = ((const float4*)wsrc)[i];
    __syncthreads();

    // lanes oc>=6 read an aliased valid slot; their acc1 is garbage, never stored
    int oc2 = oc + ((oc < 6) ? 32 : 0);

    const float* xbase = xconv + (size_t)b * EE * LL + l0 + 4 * pg;

    float acc0[4] = {}, acc1[4] = {};
    #pragma unroll 1
    for (int e0 = 0; e0 < EE; e0 += 8) {
        float4 xv[8];
        float w0[8], w1[8];
        #pragma unroll
        for (int j = 0; j < 8; j++)
            xv[j] = *(const float4*)&xbase[(size_t)(e0 + j) * LL];
        #pragma unroll
        for (int j = 0; j < 8; j++) {
            w0[j] = Ws[(e0 + j) * 38 + oc];
            w1[j] = Ws[(e0 + j) * 38 + oc2];
        }
        #pragma unroll
        for (int j = 0; j < 8; j++) {
            acc0[0] = fmaf(xv[j].x, w0[j], acc0[0]);
            acc0[1] = fmaf(xv[j].y, w0[j], acc0[1]);
            acc0[2] = fmaf(xv[j].z, w0[j], acc0[2]);
            acc0[3] = fmaf(xv[j].w, w0[j], acc0[3]);
            acc1[0] = fmaf(xv[j].x, w1[j], acc1[0]);
            acc1[1] = fmaf(xv[j].y, w1[j], acc1[1]);
            acc1[2] = fmaf(xv[j].z, w1[j], acc1[2]);
            acc1[3] = fmaf(xv[j].w, w1[j], acc1[3]);
        }
    }

    #pragma unroll
    for (int ii = 0; ii < 4; ii++) {
        int p = 4 * pg + ii;
        if (oc < 6) {
            PR[p][oc] = acc0[ii];
            BC[p][oc + 26] = acc1[ii];      // col oc+32 -> C n=oc+10
        } else {
            BC[p][oc - 6] = acc0[ii];       // cols 6..37 -> BC idx 0..25
        }
    }
    __syncthreads();

    int kb = k * 2 + b;
    for (int i = t; i < 32 * 32; i += 256) {
        int pos = i >> 5, c = i & 31;
        int j = seq_of_spatial(k, l0 + pos);
        float v = BC[pos][c];
        if (c < 16) Bbuf[((size_t)kb * LL + j) * NN + c] = v;
        else        Cbuf[((size_t)kb * LL + j) * NN + (c - 16)] = v;
    }

    for (int i = t; i < 32 * EE; i += 256) {
        int pos = i / EE;
        int e = i - pos * EE;
        float s = dtb[k * EE + e];
        const float* wr = dtw + ((size_t)k * EE + e) * RR;
        #pragma unroll
        for (int r = 0; r < RR; r++) s = fmaf(PR[pos][r], wr[r], s);
        float sp = (s > 20.f) ? s : log1pf(__expf(s));
        int j = seq_of_spatial(k, l0 + pos);
        dtbuf[((size_t)kb * LL + j) * EE + e] = sp;
    }
}

// ---------------- Kernel 4a: chunk-local scan (16 states/thread), emit (prodA, h_end) ----------------
__global__ __launch_bounds__(192) void k_scan1(const float* __restrict__ xconv_t,
                                               const float* __restrict__ dtbuf,
                                               const float* __restrict__ Bbuf,
                                               const float* __restrict__ A_log,
                                               float* __restrict__ Ap,
                                               float* __restrict__ He) {
    __shared__ __align__(16) float sB[CLEN][NN];
    int c  = blockIdx.x;
    int kb = blockIdx.y;
    int k = kb >> 1, b = kb & 1;
    int e = threadIdx.x;
    int l0 = c * CLEN;

    for (int i = e; i < CLEN * NN; i += 192)
        ((float*)sB)[i] = Bbuf[((size_t)kb * LL + l0) * NN + i];

    float An[NN], h[NN], pa[NN];
    #pragma unroll
    for (int q = 0; q < 4; q++) {
        float4 al = *(const float4*)&A_log[e * NN + q * 4];
        An[q*4+0] = -__expf(al.x); An[q*4+1] = -__expf(al.y);
        An[q*4+2] = -__expf(al.z); An[q*4+3] = -__expf(al.w);
    }
    #pragma unroll
    for (int n = 0; n < NN; n++) { h[n] = 0.f; pa[n] = 1.f; }
    __syncthreads();

    const float* dtp = dtbuf + ((size_t)kb * LL + l0) * EE + e;
    const float* ub  = xconv_t + (size_t)b * LL * EE + e;

    #pragma unroll 2
    for (int i = 0; i < CLEN; i++) {
        int l = l0 + i;
        int idx = spatial_of_seq(k, l);
        float dtv = dtp[(size_t)i * EE];
        float u   = ub[(size_t)idx * EE];
        float Bv[NN];
        #pragma unroll
        for (int q = 0; q < 4; q++)
            *(float4*)&Bv[q*4] = ((const float4*)&sB[i][0])[q];
        float dtu = dtv * u;
        #pragma unroll
        for (int n = 0; n < NN; n++) {
            float a = __expf(dtv * An[n]);
            h[n] = fmaf(a, h[n], dtu * Bv[n]);
            pa[n] *= a;
        }
    }
    size_t sid = (size_t)c * SID + kb * (EE * NN) + e * NN;
    #pragma unroll
    for (int q = 0; q < 4; q++) {
        *(float4*)&Ap[sid + q*4] = make_float4(pa[q*4], pa[q*4+1], pa[q*4+2], pa[q*4+3]);
        *(float4*)&He[sid + q*4] = make_float4(h[q*4], h[q*4+1], h[q*4+2], h[q*4+3]);
    }
}

// ---------------- Kernel 4b: sequential carry over chunks (Hi written over Ap) ----------------
__global__ __launch_bounds__(256) void k_carry(float* __restrict__ ApHi,
                                               const float* __restrict__ He) {
    int sid = blockIdx.x * 256 + threadIdx.x;
    float h = 0.f;
    #pragma unroll 8
    for (int c = 0; c < CH; c++) {
        size_t ix = (size_t)c * SID + sid;
        float a  = ApHi[ix];
        float he = He[ix];
        ApHi[ix] = h;
        h = fmaf(a, h, he);
    }
}

// ---------------- Kernel 4c: chunk-local scan with carry-in, write ys in SEQUENCE order (no atomics) ----------------
__global__ __launch_bounds__(192) void k_scan2(const float* __restrict__ xconv_t,
                                               const float* __restrict__ dtbuf,
                                               const float* __restrict__ Bbuf,
                                               const float* __restrict__ Cbuf,
                                               const float* __restrict__ A_log,
                                               const float* __restrict__ Dskip,
                                               const float* __restrict__ Hi,
                                               float* __restrict__ ys) {
    __shared__ __align__(16) float sB[CLEN][NN];
    __shared__ __align__(16) float sC[CLEN][NN];
    int c  = blockIdx.x;
    int kb = blockIdx.y;
    int k = kb >> 1, b = kb & 1;
    int e = threadIdx.x;
    int l0 = c * CLEN;

    for (int i = e; i < CLEN * NN; i += 192) {
        ((float*)sB)[i] = Bbuf[((size_t)kb * LL + l0) * NN + i];
        ((float*)sC)[i] = Cbuf[((size_t)kb * LL + l0) * NN + i];
    }

    float An[NN], h[NN];
    #pragma unroll
    for (int q = 0; q < 4; q++) {
        float4 al = *(const float4*)&A_log[e * NN + q * 4];
        An[q*4+0] = -__expf(al.x); An[q*4+1] = -__expf(al.y);
        An[q*4+2] = -__expf(al.z); An[q*4+3] = -__expf(al.w);
    }
    size_t sid = (size_t)c * SID + kb * (EE * NN) + e * NN;
    #pragma unroll
    for (int q = 0; q < 4; q++) {
        float4 hv = *(const float4*)&Hi[sid + q*4];
        h[q*4+0] = hv.x; h[q*4+1] = hv.y; h[q*4+2] = hv.z; h[q*4+3] = hv.w;
    }
    float Dv = Dskip[e];
    __syncthreads();

    const float* dtp = dtbuf + ((size_t)kb * LL + l0) * EE + e;
    const float* ub  = xconv_t + (size_t)b * LL * EE + e;
    float* ysb       = ys + ((size_t)kb * LL + l0) * EE + e;

    #pragma unroll 2
    for (int i = 0; i < CLEN; i++) {
        int l = l0 + i;
        int idx = spatial_of_seq(k, l);
        float dtv = dtp[(size_t)i * EE];
        float u   = ub[(size_t)idx * EE];
        float Bv[NN], Cv[NN];
        #pragma unroll
        for (int q = 0; q < 4; q++) {
            *(float4*)&Bv[q*4] = ((const float4*)&sB[i][0])[q];
            *(float4*)&Cv[q*4] = ((const float4*)&sC[i][0])[q];
        }
        float dtu = dtv * u;
        float y = u * Dv;
        #pragma unroll
        for (int n = 0; n < NN; n++) {
            float a = __expf(dtv * An[n]);
            h[n] = fmaf(a, h[n], dtu * Bv[n]);
            y = fmaf(h[n], Cv[n], y);
        }
        ysb[(size_t)i * EE] = y;
    }
}

// ---------------- Kernel 5: 4-direction gather + LayerNorm + silu(z) gate + out_proj ----------------
__global__ __launch_bounds__(256) void k_out(const float* __restrict__ ys,
                                             const float* __restrict__ zb,
                                             const float* __restrict__ gamma,
                                             const float* __restrict__ beta,
                                             const float* __restrict__ W2,
                                             float* __restrict__ out) {
    __shared__ __align__(16) float sbuf[32][196];  // 196: rows 16B-aligned, 49%32 bank-safe
    int b  = blockIdx.x >> 7;
    int l0 = (blockIdx.x & 127) * 32;
    int t  = threadIdx.x;
    int wv = t >> 6, lane = t & 63;

    for (int li = 0; li < 32; li += 4) {
        int l = l0 + li + wv;
        int p = ((l & 63) << 6) | (l >> 6);
        const float* r0 = ys + ((size_t)(0 + b) * LL + l) * EE;
        const float* r1 = ys + ((size_t)(2 + b) * LL + (LL - 1 - l)) * EE;
        const float* r2 = ys + ((size_t)(4 + b) * LL + p) * EE;
        const float* r3 = ys + ((size_t)(6 + b) * LL + (LL - 1 - p)) * EE;
        const float* zrow = zb + ((size_t)b * LL + l) * EE;
        float v[3], zv[3];
        float s = 0.f;
        #pragma unroll
        for (int j = 0; j < 3; j++) {
            int e = lane + 64 * j;
            v[j] = r0[e] + r1[e] + r2[e] + r3[e];
            zv[j] = zrow[e];
            s += v[j];
        }
        for (int m = 1; m < 64; m <<= 1) s += __shfl_xor(s, m);
        float mu = s * (1.f / EE);
        float q = 0.f;
        #pragma unroll
        for (int j = 0; j < 3; j++) { float d = v[j] - mu; q = fmaf(d, d, q); }
        for (int m = 1; m < 64; m <<= 1) q += __shfl_xor(q, m);
        float rs = rsqrtf(q * (1.f / EE) + 1e-5f);
        #pragma unroll
        for (int j = 0; j < 3; j++) {
            int e = lane + 64 * j;
            float yn = (v[j] - mu) * rs * gamma[e] + beta[e];
            float zz = zv[j];
            float sil = zz / (1.f + __expf(-zz));
            sbuf[li + wv][e] = yn * sil;
        }
    }
    __syncthreads();
    for (int o = t; o < DM * 32; o += 256) {
        int d = o >> 5, c = o & 31;
        const float* wr = W2 + (size_t)d * EE;
        float acc = 0.f;
        for (int e = 0; e < EE; e += 4) {
            float4 sv = *(const float4*)&sbuf[c][e];
            float4 wv4 = *(const float4*)&wr[e];
            acc = fmaf(sv.x, wv4.x, acc);
            acc = fmaf(sv.y, wv4.y, acc);
            acc = fmaf(sv.z, wv4.z, acc);
            acc = fmaf(sv.w, wv4.w, acc);
        }
        out[((size_t)b * DM + d) * LL + l0 + c] = acc;
    }
}

extern "C" void kernel_launch(void* const* d_in, const int* in_sizes, int n_in,
                              void* d_out, int out_size, void* d_ws, size_t ws_size,
                              hipStream_t stream) {
    const float* x      = (const float*)d_in[0];
    const float* in_w   = (const float*)d_in[1];
    const float* conv_w = (const float*)d_in[2];
    const float* conv_b = (const float*)d_in[3];
    const float* xpw    = (const float*)d_in[4];
    const float* dtw    = (const float*)d_in[5];
    const float* dtbias = (const float*)d_in[6];
    const float* A_log  = (const float*)d_in[7];
    const float* Dsk    = (const float*)d_in[8];
    const float* gamma  = (const float*)d_in[9];
    const float* beta   = (const float*)d_in[10];
    const float* W2     = (const float*)d_in[11];
    float* out = (float*)d_out;

    // Workspace layout with lifetime-based aliasing (all sizes in floats).
    // R region hosts xbuf/xconv/He early, then becomes ys after they die.
    // Every ws byte read is written earlier in the same call (0xAA poison safe).
    float* ws      = (float*)d_ws;
    float* zbuf    = ws;                                   // B*L*E
    float* xconv_t = zbuf    + (size_t)BB * LL * EE;       // B*L*E
    float* dtbuf   = xconv_t + (size_t)BB * LL * EE;       // KB*L*E
    float* Bbuf    = dtbuf   + (size_t)KBB * LL * EE;      // KB*L*N
    float* Cbuf    = Bbuf    + (size_t)KBB * LL * NN;      // KB*L*N
    float* ApHi    = Cbuf    + (size_t)KBB * LL * NN;      // CH*SID
    float* R       = ApHi    + (size_t)CH * SID;           // KB*L*E
    float* ys      = R;
    float* xbuf    = R;                                    // dead after k_conv
    float* xconv   = R + (size_t)BB * EE * LL;             // dead after k_proj
    float* He      = R + 2 * (size_t)BB * EE * LL;         // dead after k_carry

    k_inproj<<<dim3(128, 6), 256, 0, stream>>>(x, in_w, xbuf, zbuf);
    k_conv<<<dim3(128, 6, 2), 256, 0, stream>>>(xbuf, conv_w, conv_b, xconv, xconv_t);
    k_proj<<<dim3(128, 2, 4), 256, 0, stream>>>(xconv, xpw, dtw, dtbias, dtbuf, Bbuf, Cbuf);
    k_scan1<<<dim3(CH, KBB), 192, 0, stream>>>(xconv_t, dtbuf, Bbuf, A_log, ApHi, He);
    k_carry<<<SID / 256, 256, 0, stream>>>(ApHi, He);
    k_scan2<<<dim3(CH, KBB), 192, 0, stream>>>(xconv_t, dtbuf, Bbuf, Cbuf, A_log, Dsk, ApHi, ys);
    k_out<<<BB * (LL / 32), 256, 0, stream>>>(ys, zbuf, gamma, beta, W2, out);
}

// Round 14
// 268.992 us; speedup vs baseline: 1.0478x; 1.0028x over previous
//
#include <hip/hip_runtime.h>

#define LL 4096
#define HH 64
#define WWD 64
#define DM 96
#define EE 192
#define NN 16
#define RR 6
#define KBB 8   // N_DIRS * B
#define BB 2
#define CH 128  // number of chunks
#define CLEN 32 // chunk length
#define SID (KBB * EE * NN)  // 24576 states

// ---------------- Kernel 1: in_proj GEMM (float4 LDS) ----------------
__global__ __launch_bounds__(256) void k_inproj(const float* __restrict__ x,
                                                const float* __restrict__ W,
                                                float* __restrict__ xbuf,
                                                float* __restrict__ zbuf) {
    __shared__ __align__(16) float As[96][64];
    __shared__ __align__(16) float Ws[96][64];
    int bm = blockIdx.x;
    int bn = blockIdx.y;
    int l0 = bm * 64;
    int b  = l0 >> 12;
    int lb = l0 & (LL - 1);
    int j0 = bn * 64;
    int t  = threadIdx.x;

    for (int i = t; i < 96 * 16; i += 256) {
        int d = i >> 4, q = i & 15;
        *(float4*)&As[d][4 * q] = *(const float4*)&x[((size_t)b * 96 + d) * LL + lb + 4 * q];
    }
    for (int i = t; i < 96 * 64; i += 256) {
        int jn = i / 96, d = i - jn * 96;
        Ws[d][jn] = W[(size_t)(j0 + jn) * 96 + d];
    }
    __syncthreads();

    int tx = t & 15, ty = t >> 4;
    float acc[4][4] = {};
    for (int d = 0; d < 96; d++) {
        float4 av = *(const float4*)&As[d][ty * 4];
        float4 bv = *(const float4*)&Ws[d][tx * 4];
        float a[4] = {av.x, av.y, av.z, av.w};
        float bbv[4] = {bv.x, bv.y, bv.z, bv.w};
        for (int i = 0; i < 4; i++)
            for (int j = 0; j < 4; j++) acc[i][j] = fmaf(a[i], bbv[j], acc[i][j]);
    }
    for (int i = 0; i < 4; i++) {
        int l = lb + ty * 4 + i;
        for (int j = 0; j < 4; j++) {
            int jj = j0 + tx * 4 + j;
            if (jj < EE)
                xbuf[((size_t)b * EE + jj) * LL + l] = acc[i][j];
            else
                zbuf[((size_t)b * LL + l) * EE + (jj - EE)] = acc[i][j];
        }
    }
}

// ---------------- Kernel 2: depthwise 3x3 conv + bias + SiLU -> transposed out only ----------------
__global__ __launch_bounds__(256) void k_conv(const float* __restrict__ xbuf,
                                              const float* __restrict__ cw,
                                              const float* __restrict__ cb,
                                              float* __restrict__ xconv_t) {
    __shared__ float T[32][33];
    int l0 = blockIdx.x * 32;
    int e0 = blockIdx.y * 32;
    int b  = blockIdx.z;
    int t  = threadIdx.x;
    int tp = t & 31, teo = t >> 5;

    int pos = l0 + tp;
    int h = pos >> 6, w = pos & 63;
    #pragma unroll
    for (int j = 0; j < 4; j++) {
        int ee = j * 8 + teo;
        int e = e0 + ee;
        const float* src = xbuf + ((size_t)b * EE + e) * LL;
        const float* wgt = cw + e * 9;
        float acc = cb[e];
        #pragma unroll
        for (int dh = -1; dh <= 1; dh++) {
            int hh = h + dh;
            if (hh < 0 || hh >= HH) continue;
            #pragma unroll
            for (int dw = -1; dw <= 1; dw++) {
                int w2 = w + dw;
                if (w2 < 0 || w2 >= WWD) continue;
                acc = fmaf(src[hh * WWD + w2], wgt[(dh + 1) * 3 + (dw + 1)], acc);
            }
        }
        float v = acc / (1.f + __expf(-acc));
        T[ee][tp] = v;
    }
    __syncthreads();
    for (int i = t; i < 32 * 32; i += 256) {
        int p = i >> 5, ee = i & 31;
        xconv_t[((size_t)b * LL + l0 + p) * EE + e0 + ee] = T[ee][p];
    }
}

__device__ __forceinline__ int seq_of_spatial(int k, int idx) {
    if (k == 0) return idx;
    if (k == 1) return LL - 1 - idx;
    int p = ((idx & 63) << 6) | (idx >> 6);
    if (k == 2) return p;
    return LL - 1 - p;
}

__device__ __forceinline__ int spatial_of_seq(int k, int l) {
    int lp = (k & 1) ? (LL - 1 - l) : l;
    return (k >= 2) ? (((lp & 63) << 6) | (lp >> 6)) : lp;
}

// ---------------- Kernel 3 v8: x_proj + dt_proj + softplus (X staged in LDS) ----------------
// Block tile of X (32pos x 192e) is CONTIGUOUS in xconv_t -> coalesced float4
// stage into LDS; inner loop is pure LDS+FMA (no global loads to hide).
// X reads broadcast (2 addrs/wave); W reads stride-1; X pad 196 -> disjoint
// bank quads for the 8 distinct row reads. 58.3KB LDS -> 2 blocks/CU.
__global__ __launch_bounds__(256, 2) void k_proj(const float* __restrict__ xconv_t,
                                                 const float* __restrict__ xpw,
                                                 const float* __restrict__ dtw,
                                                 const float* __restrict__ dtb,
                                                 float* __restrict__ dtbuf,
                                                 float* __restrict__ Bbuf,
                                                 float* __restrict__ Cbuf) {
    __shared__ __align__(16) float Ws[EE * 38 + 40];
    __shared__ __align__(16) float X[32][196];
    __shared__ float PR[32][8];    // dt_low  (cols 0..5)
    __shared__ float BC[32][33];   // B(0..15) C(16..31)
    int l0 = blockIdx.x * 32;
    int b  = blockIdx.y;
    int k  = blockIdx.z;
    int t  = threadIdx.x;
    int pg = t >> 5;       // 0..7 -> 4 positions each
    int oc = t & 31;       // col0 = oc; col1 = oc+32 (lanes oc<6)

    const float* wsrc = xpw + (size_t)k * EE * 38;
    for (int i = t; i < (EE * 38) / 4; i += 256)
        ((float4*)Ws)[i] = ((const float4*)wsrc)[i];
    const float* xsrc = xconv_t + ((size_t)b * LL + l0) * EE;
    for (int i = t; i < (32 * EE) / 4; i += 256) {
        float4 v = ((const float4*)xsrc)[i];
        int pos = i / 48, e4 = i % 48;
        *(float4*)&X[pos][4 * e4] = v;
    }
    __syncthreads();

    // lanes oc>=6 read an aliased valid slot; their acc1 is garbage, never stored
    int oc2 = oc + ((oc < 6) ? 32 : 0);

    float acc0[4] = {}, acc1[4] = {};
    #pragma unroll 2
    for (int e0 = 0; e0 < EE; e0 += 4) {
        float4 xv[4];
        #pragma unroll
        for (int ii = 0; ii < 4; ii++)
            xv[ii] = *(const float4*)&X[4 * pg + ii][e0];
        float w0[4], w1[4];
        #pragma unroll
        for (int j = 0; j < 4; j++) {
            w0[j] = Ws[(e0 + j) * 38 + oc];
            w1[j] = Ws[(e0 + j) * 38 + oc2];
        }
        #pragma unroll
        for (int ii = 0; ii < 4; ii++) {
            acc0[ii] = fmaf(xv[ii].x, w0[0], acc0[ii]);
            acc0[ii] = fmaf(xv[ii].y, w0[1], acc0[ii]);
            acc0[ii] = fmaf(xv[ii].z, w0[2], acc0[ii]);
            acc0[ii] = fmaf(xv[ii].w, w0[3], acc0[ii]);
            acc1[ii] = fmaf(xv[ii].x, w1[0], acc1[ii]);
            acc1[ii] = fmaf(xv[ii].y, w1[1], acc1[ii]);
            acc1[ii] = fmaf(xv[ii].z, w1[2], acc1[ii]);
            acc1[ii] = fmaf(xv[ii].w, w1[3], acc1[ii]);
        }
    }

    #pragma unroll
    for (int ii = 0; ii < 4; ii++) {
        int p = 4 * pg + ii;
        if (oc < 6) {
            PR[p][oc] = acc0[ii];
            BC[p][oc + 26] = acc1[ii];      // col oc+32 -> C n=oc+10
        } else {
            BC[p][oc - 6] = acc0[ii];       // cols 6..37 -> BC idx 0..25
        }
    }
    __syncthreads();

    int kb = k * 2 + b;
    for (int i = t; i < 32 * 32; i += 256) {
        int pos = i >> 5, c = i & 31;
        int j = seq_of_spatial(k, l0 + pos);
        float v = BC[pos][c];
        if (c < 16) Bbuf[((size_t)kb * LL + j) * NN + c] = v;
        else        Cbuf[((size_t)kb * LL + j) * NN + (c - 16)] = v;
    }

    for (int i = t; i < 32 * EE; i += 256) {
        int pos = i / EE;
        int e = i - pos * EE;
        float s = dtb[k * EE + e];
        const float* wr = dtw + ((size_t)k * EE + e) * RR;
        #pragma unroll
        for (int r = 0; r < RR; r++) s = fmaf(PR[pos][r], wr[r], s);
        float sp = (s > 20.f) ? s : log1pf(__expf(s));
        int j = seq_of_spatial(k, l0 + pos);
        dtbuf[((size_t)kb * LL + j) * EE + e] = sp;
    }
}

// ---------------- Kernel 4a: chunk-local scan (16 states/thread), emit (prodA, h_end) ----------------
__global__ __launch_bounds__(192) void k_scan1(const float* __restrict__ xconv_t,
                                               const float* __restrict__ dtbuf,
                                               const float* __restrict__ Bbuf,
                                               const float* __restrict__ A_log,
                                               float* __restrict__ Ap,
                                               float* __restrict__ He) {
    __shared__ __align__(16) float sB[CLEN][NN];
    int c  = blockIdx.x;
    int kb = blockIdx.y;
    int k = kb >> 1, b = kb & 1;
    int e = threadIdx.x;
    int l0 = c * CLEN;

    for (int i = e; i < CLEN * NN; i += 192)
        ((float*)sB)[i] = Bbuf[((size_t)kb * LL + l0) * NN + i];

    float An[NN], h[NN], pa[NN];
    #pragma unroll
    for (int q = 0; q < 4; q++) {
        float4 al = *(const float4*)&A_log[e * NN + q * 4];
        An[q*4+0] = -__expf(al.x); An[q*4+1] = -__expf(al.y);
        An[q*4+2] = -__expf(al.z); An[q*4+3] = -__expf(al.w);
    }
    #pragma unroll
    for (int n = 0; n < NN; n++) { h[n] = 0.f; pa[n] = 1.f; }
    __syncthreads();

    const float* dtp = dtbuf + ((size_t)kb * LL + l0) * EE + e;
    const float* ub  = xconv_t + (size_t)b * LL * EE + e;

    #pragma unroll 2
    for (int i = 0; i < CLEN; i++) {
        int l = l0 + i;
        int idx = spatial_of_seq(k, l);
        float dtv = dtp[(size_t)i * EE];
        float u   = ub[(size_t)idx * EE];
        float Bv[NN];
        #pragma unroll
        for (int q = 0; q < 4; q++)
            *(float4*)&Bv[q*4] = ((const float4*)&sB[i][0])[q];
        float dtu = dtv * u;
        #pragma unroll
        for (int n = 0; n < NN; n++) {
            float a = __expf(dtv * An[n]);
            h[n] = fmaf(a, h[n], dtu * Bv[n]);
            pa[n] *= a;
        }
    }
    size_t sid = (size_t)c * SID + kb * (EE * NN) + e * NN;
    #pragma unroll
    for (int q = 0; q < 4; q++) {
        *(float4*)&Ap[sid + q*4] = make_float4(pa[q*4], pa[q*4+1], pa[q*4+2], pa[q*4+3]);
        *(float4*)&He[sid + q*4] = make_float4(h[q*4], h[q*4+1], h[q*4+2], h[q*4+3]);
    }
}

// ---------------- Kernel 4b: sequential carry over chunks (Hi written over Ap) ----------------
__global__ __launch_bounds__(256) void k_carry(float* __restrict__ ApHi,
                                               const float* __restrict__ He) {
    int sid = blockIdx.x * 256 + threadIdx.x;
    float h = 0.f;
    #pragma unroll 8
    for (int c = 0; c < CH; c++) {
        size_t ix = (size_t)c * SID + sid;
        float a  = ApHi[ix];
        float he = He[ix];
        ApHi[ix] = h;
        h = fmaf(a, h, he);
    }
}

// ---------------- Kernel 4c: chunk-local scan with carry-in, write ys in SEQUENCE order (no atomics) ----------------
__global__ __launch_bounds__(192) void k_scan2(const float* __restrict__ xconv_t,
                                               const float* __restrict__ dtbuf,
                                               const float* __restrict__ Bbuf,
                                               const float* __restrict__ Cbuf,
                                               const float* __restrict__ A_log,
                                               const float* __restrict__ Dskip,
                                               const float* __restrict__ Hi,
                                               float* __restrict__ ys) {
    __shared__ __align__(16) float sB[CLEN][NN];
    __shared__ __align__(16) float sC[CLEN][NN];
    int c  = blockIdx.x;
    int kb = blockIdx.y;
    int k = kb >> 1, b = kb & 1;
    int e = threadIdx.x;
    int l0 = c * CLEN;

    for (int i = e; i < CLEN * NN; i += 192) {
        ((float*)sB)[i] = Bbuf[((size_t)kb * LL + l0) * NN + i];
        ((float*)sC)[i] = Cbuf[((size_t)kb * LL + l0) * NN + i];
    }

    float An[NN], h[NN];
    #pragma unroll
    for (int q = 0; q < 4; q++) {
        float4 al = *(const float4*)&A_log[e * NN + q * 4];
        An[q*4+0] = -__expf(al.x); An[q*4+1] = -__expf(al.y);
        An[q*4+2] = -__expf(al.z); An[q*4+3] = -__expf(al.w);
    }
    size_t sid = (size_t)c * SID + kb * (EE * NN) + e * NN;
    #pragma unroll
    for (int q = 0; q < 4; q++) {
        float4 hv = *(const float4*)&Hi[sid + q*4];
        h[q*4+0] = hv.x; h[q*4+1] = hv.y; h[q*4+2] = hv.z; h[q*4+3] = hv.w;
    }
    float Dv = Dskip[e];
    __syncthreads();

    const float* dtp = dtbuf + ((size_t)kb * LL + l0) * EE + e;
    const float* ub  = xconv_t + (size_t)b * LL * EE + e;
    float* ysb       = ys + ((size_t)kb * LL + l0) * EE + e;

    #pragma unroll 2
    for (int i = 0; i < CLEN; i++) {
        int l = l0 + i;
        int idx = spatial_of_seq(k, l);
        float dtv = dtp[(size_t)i * EE];
        float u   = ub[(size_t)idx * EE];
        float Bv[NN], Cv[NN];
        #pragma unroll
        for (int q = 0; q < 4; q++) {
            *(float4*)&Bv[q*4] = ((const float4*)&sB[i][0])[q];
            *(float4*)&Cv[q*4] = ((const float4*)&sC[i][0])[q];
        }
        float dtu = dtv * u;
        float y = u * Dv;
        #pragma unroll
        for (int n = 0; n < NN; n++) {
            float a = __expf(dtv * An[n]);
            h[n] = fmaf(a, h[n], dtu * Bv[n]);
            y = fmaf(h[n], Cv[n], y);
        }
        ysb[(size_t)i * EE] = y;
    }
}

// ---------------- Kernel 5: 4-direction gather + LayerNorm + silu(z) gate + out_proj ----------------
__global__ __launch_bounds__(256) void k_out(const float* __restrict__ ys,
                                             const float* __restrict__ zb,
                                             const float* __restrict__ gamma,
                                             const float* __restrict__ beta,
                                             const float* __restrict__ W2,
                                             float* __restrict__ out) {
    __shared__ __align__(16) float sbuf[32][196];  // 196: rows 16B-aligned, bank-safe
    int b  = blockIdx.x >> 7;
    int l0 = (blockIdx.x & 127) * 32;
    int t  = threadIdx.x;
    int wv = t >> 6, lane = t & 63;

    for (int li = 0; li < 32; li += 4) {
        int l = l0 + li + wv;
        int p = ((l & 63) << 6) | (l >> 6);
        const float* r0 = ys + ((size_t)(0 + b) * LL + l) * EE;
        const float* r1 = ys + ((size_t)(2 + b) * LL + (LL - 1 - l)) * EE;
        const float* r2 = ys + ((size_t)(4 + b) * LL + p) * EE;
        const float* r3 = ys + ((size_t)(6 + b) * LL + (LL - 1 - p)) * EE;
        const float* zrow = zb + ((size_t)b * LL + l) * EE;
        float v[3], zv[3];
        float s = 0.f;
        #pragma unroll
        for (int j = 0; j < 3; j++) {
            int e = lane + 64 * j;
            v[j] = r0[e] + r1[e] + r2[e] + r3[e];
            zv[j] = zrow[e];
            s += v[j];
        }
        for (int m = 1; m < 64; m <<= 1) s += __shfl_xor(s, m);
        float mu = s * (1.f / EE);
        float q = 0.f;
        #pragma unroll
        for (int j = 0; j < 3; j++) { float d = v[j] - mu; q = fmaf(d, d, q); }
        for (int m = 1; m < 64; m <<= 1) q += __shfl_xor(q, m);
        float rs = rsqrtf(q * (1.f / EE) + 1e-5f);
        #pragma unroll
        for (int j = 0; j < 3; j++) {
            int e = lane + 64 * j;
            float yn = (v[j] - mu) * rs * gamma[e] + beta[e];
            float zz = zv[j];
            float sil = zz / (1.f + __expf(-zz));
            sbuf[li + wv][e] = yn * sil;
        }
    }
    __syncthreads();
    for (int o = t; o < DM * 32; o += 256) {
        int d = o >> 5, c = o & 31;
        const float* wr = W2 + (size_t)d * EE;
        float acc = 0.f;
        for (int e = 0; e < EE; e += 4) {
            float4 sv = *(const float4*)&sbuf[c][e];
            float4 wv4 = *(const float4*)&wr[e];
            acc = fmaf(sv.x, wv4.x, acc);
            acc = fmaf(sv.y, wv4.y, acc);
            acc = fmaf(sv.z, wv4.z, acc);
            acc = fmaf(sv.w, wv4.w, acc);
        }
        out[((size_t)b * DM + d) * LL + l0 + c] = acc;
    }
}

extern "C" void kernel_launch(void* const* d_in, const int* in_sizes, int n_in,
                              void* d_out, int out_size, void* d_ws, size_t ws_size,
                              hipStream_t stream) {
    const float* x      = (const float*)d_in[0];
    const float* in_w   = (const float*)d_in[1];
    const float* conv_w = (const float*)d_in[2];
    const float* conv_b = (const float*)d_in[3];
    const float* xpw    = (const float*)d_in[4];
    const float* dtw    = (const float*)d_in[5];
    const float* dtbias = (const float*)d_in[6];
    const float* A_log  = (const float*)d_in[7];
    const float* Dsk    = (const float*)d_in[8];
    const float* gamma  = (const float*)d_in[9];
    const float* beta   = (const float*)d_in[10];
    const float* W2     = (const float*)d_in[11];
    float* out = (float*)d_out;

    // Workspace layout with lifetime-based aliasing (all sizes in floats).
    // R region hosts xbuf/He early, then becomes ys after they die.
    // Every ws byte read is written earlier in the same call (0xAA poison safe).
    float* ws      = (float*)d_ws;
    float* zbuf    = ws;                                   // B*L*E
    float* xconv_t = zbuf    + (size_t)BB * LL * EE;       // B*L*E
    float* dtbuf   = xconv_t + (size_t)BB * LL * EE;       // KB*L*E
    float* Bbuf    = dtbuf   + (size_t)KBB * LL * EE;      // KB*L*N
    float* Cbuf    = Bbuf    + (size_t)KBB * LL * NN;      // KB*L*N
    float* ApHi    = Cbuf    + (size_t)KBB * LL * NN;      // CH*SID
    float* R       = ApHi    + (size_t)CH * SID;           // KB*L*E
    float* ys      = R;
    float* xbuf    = R;                                    // dead after k_conv
    float* He      = R + 2 * (size_t)BB * EE * LL;         // dead after k_carry

    k_inproj<<<dim3(128, 6), 256, 0, stream>>>(x, in_w, xbuf, zbuf);
    k_conv<<<dim3(128, 6, 2), 256, 0, stream>>>(xbuf, conv_w, conv_b, xconv_t);
    k_proj<<<dim3(128, 2, 4), 256, 0, stream>>>(xconv_t, xpw, dtw, dtbias, dtbuf, Bbuf, Cbuf);
    k_scan1<<<dim3(CH, KBB), 192, 0, stream>>>(xconv_t, dtbuf, Bbuf, A_log, ApHi, He);
    k_carry<<<SID / 256, 256, 0, stream>>>(ApHi, He);
    k_scan2<<<dim3(CH, KBB), 192, 0, stream>>>(xconv_t, dtbuf, Bbuf, Cbuf, A_log, Dsk, ApHi, ys);
    k_out<<<BB * (LL / 32), 256, 0, stream>>>(ys, zbuf, gamma, beta, W2, out);
}